// Round 1
// baseline (3446.014 us; speedup 1.0000x reference)
//
#include <hip/hip_runtime.h>
#include <hip/hip_bf16.h>

#define N_NODES 50000
#define N_EDGES 640000
#define D 128
#define NPAD 50048   // 782 * 64, pad rows for 64-row GEMM blocks
#define LAYERS 3

typedef __attribute__((ext_vector_type(4))) float f32x4;
typedef __attribute__((ext_vector_type(8))) short bf16x8;

static __device__ __forceinline__ short f2bf(float f) {
    union { float f; unsigned u; } x; x.f = f;
    unsigned r = x.u + 0x7fffu + ((x.u >> 16) & 1u);  // RNE
    return (short)(r >> 16);
}

// ---------------- h = x ----------------
__global__ void copy_f4(const f32x4* __restrict__ in, f32x4* __restrict__ out) {
    int t = blockIdx.x * 256 + threadIdx.x;
    out[t] = in[t];
}

// ---------------- pre-transpose + bf16-cast weights: wt[m][c][k] = W[m][k][c] ----------------
__global__ void prepw_kernel(const float* __restrict__ W1, const float* __restrict__ W2,
                             short* __restrict__ wt) {
    int t = blockIdx.x * 256 + threadIdx.x;
    if (t >= 6 * 16384) return;
    int m = t >> 14;           // 0..5 (0..2 = W1 layers, 3..5 = W2 layers)
    int rem = t & 16383;
    int c = rem >> 7, k = rem & 127;
    const float* src = (m < 3) ? (W1 + m * 16384) : (W2 + (m - 3) * 16384);
    wt[m * 16384 + c * 128 + k] = f2bf(src[k * 128 + c]);
}

// ---------------- scatter: agg[dst] += h[src] ----------------
__global__ void scatter_kernel(const int* __restrict__ src, const int* __restrict__ dst,
                               const f32x4* __restrict__ h, float* __restrict__ agg) {
    int t = blockIdx.x * 256 + threadIdx.x;
    int e = t >> 5;
    int c = t & 31;
    if (e >= N_EDGES) return;
    int s = src[e], d = dst[e];
    f32x4 v = h[s * 32 + c];
    float* p = agg + (size_t)d * D + c * 4;
    atomicAdd(p + 0, v.x);
    atomicAdd(p + 1, v.y);
    atomicAdd(p + 2, v.z);
    atomicAdd(p + 3, v.w);
}

// ---------------- z = bf16((1+eps)*h + agg), zero pad rows ----------------
__global__ void prep_kernel(const f32x4* __restrict__ h, const f32x4* __restrict__ agg,
                            const float* __restrict__ epsArr, int layer,
                            bf16x8* __restrict__ z) {
    int t = blockIdx.x * 256 + threadIdx.x;
    if (t >= NPAD * 16) return;
    bf16x8 o;
    if (t < N_NODES * 16) {
        float s = 1.0f + epsArr[layer];
        f32x4 h0 = h[2 * t], h1 = h[2 * t + 1];
        f32x4 g0 = agg[2 * t], g1 = agg[2 * t + 1];
        o[0] = f2bf(s * h0.x + g0.x);
        o[1] = f2bf(s * h0.y + g0.y);
        o[2] = f2bf(s * h0.z + g0.z);
        o[3] = f2bf(s * h0.w + g0.w);
        o[4] = f2bf(s * h1.x + g1.x);
        o[5] = f2bf(s * h1.y + g1.y);
        o[6] = f2bf(s * h1.z + g1.z);
        o[7] = f2bf(s * h1.w + g1.w);
    } else {
        o = (bf16x8)(short)0;
    }
    z[t] = o;
}

// ---------------- GEMM: out = act(A @ W + bias), A [NPAD][128] bf16, Wt [c][k] bf16 ----------------
// wave handles 16 rows x 128 cols; block = 4 waves = 64 rows
template <bool RELU, bool OUTBF>
__global__ __launch_bounds__(256) void gemm_kernel(const short* __restrict__ A,
                                                   const short* __restrict__ Wt,
                                                   const float* __restrict__ bias,
                                                   short* __restrict__ obf,
                                                   float* __restrict__ of) {
    int wave = threadIdx.x >> 6, lane = threadIdx.x & 63;
    int rowBase = blockIdx.x * 64 + wave * 16;
    int r = lane & 15, kq = lane >> 4;

    const short* Ar = A + (size_t)(rowBase + r) * D + kq * 8;
    bf16x8 a0 = *(const bf16x8*)(Ar);
    bf16x8 a1 = *(const bf16x8*)(Ar + 32);
    bf16x8 a2 = *(const bf16x8*)(Ar + 64);
    bf16x8 a3 = *(const bf16x8*)(Ar + 96);

#pragma unroll
    for (int ct = 0; ct < 8; ++ct) {
        int c = ct * 16 + r;
        const short* Wc = Wt + c * D + kq * 8;
        f32x4 acc = {0.f, 0.f, 0.f, 0.f};
        acc = __builtin_amdgcn_mfma_f32_16x16x32_bf16(a0, *(const bf16x8*)(Wc), acc, 0, 0, 0);
        acc = __builtin_amdgcn_mfma_f32_16x16x32_bf16(a1, *(const bf16x8*)(Wc + 32), acc, 0, 0, 0);
        acc = __builtin_amdgcn_mfma_f32_16x16x32_bf16(a2, *(const bf16x8*)(Wc + 64), acc, 0, 0, 0);
        acc = __builtin_amdgcn_mfma_f32_16x16x32_bf16(a3, *(const bf16x8*)(Wc + 96), acc, 0, 0, 0);
        float bcol = bias[c];
        int orow = rowBase + kq * 4;
#pragma unroll
        for (int j = 0; j < 4; ++j) {
            float v = acc[j] + bcol;
            if (RELU) v = fmaxf(v, 0.0f);
            int rr = orow + j;
            if (rr < N_NODES) {
                if (OUTBF) obf[(size_t)rr * D + c] = f2bf(v);
                else       of[(size_t)rr * D + c] = v;
            }
        }
    }
}

// ---------------- LN (+ skip LN + relu) + residual: h += y ----------------
__global__ void ln_res_kernel(const f32x4* __restrict__ v, f32x4* __restrict__ h,
                              const float* __restrict__ g1, const float* __restrict__ b1,
                              const float* __restrict__ g2, const float* __restrict__ b2,
                              int hasSkip) {
    int t = blockIdx.x * 256 + threadIdx.x;
    int row = t >> 5, lane = t & 31;
    if (row >= N_NODES) return;
    f32x4 x = v[(size_t)row * 32 + lane];
    float s = x.x + x.y + x.z + x.w;
    float q = x.x * x.x + x.y * x.y + x.z * x.z + x.w * x.w;
#pragma unroll
    for (int m = 1; m < 32; m <<= 1) {
        s += __shfl_xor(s, m, 64);
        q += __shfl_xor(q, m, 64);
    }
    float mu = s * (1.0f / D);
    float rs = rsqrtf(q * (1.0f / D) - mu * mu + 1e-5f);
    int c = lane * 4;
    f32x4 ga = *(const f32x4*)(g1 + c);
    f32x4 ba = *(const f32x4*)(b1 + c);
    f32x4 y;
    y.x = (x.x - mu) * rs * ga.x + ba.x;
    y.y = (x.y - mu) * rs * ga.y + ba.y;
    y.z = (x.z - mu) * rs * ga.z + ba.z;
    y.w = (x.w - mu) * rs * ga.w + ba.w;
    if (hasSkip) {
        float s2 = y.x + y.y + y.z + y.w;
        float q2 = y.x * y.x + y.y * y.y + y.z * y.z + y.w * y.w;
#pragma unroll
        for (int m = 1; m < 32; m <<= 1) {
            s2 += __shfl_xor(s2, m, 64);
            q2 += __shfl_xor(q2, m, 64);
        }
        float mu2 = s2 * (1.0f / D);
        float rs2 = rsqrtf(q2 * (1.0f / D) - mu2 * mu2 + 1e-5f);
        f32x4 gb = *(const f32x4*)(g2 + c);
        f32x4 bb = *(const f32x4*)(b2 + c);
        y.x = fmaxf((y.x - mu2) * rs2 * gb.x + bb.x, 0.0f);
        y.y = fmaxf((y.y - mu2) * rs2 * gb.y + bb.y, 0.0f);
        y.z = fmaxf((y.z - mu2) * rs2 * gb.z + bb.z, 0.0f);
        y.w = fmaxf((y.w - mu2) * rs2 * gb.w + bb.w, 0.0f);
    }
    f32x4 ho = h[(size_t)row * 32 + lane];
    ho.x += y.x; ho.y += y.y; ho.z += y.z; ho.w += y.w;
    h[(size_t)row * 32 + lane] = ho;
}

extern "C" void kernel_launch(void* const* d_in, const int* in_sizes, int n_in,
                              void* d_out, int out_size, void* d_ws, size_t ws_size,
                              hipStream_t stream) {
    const float* x   = (const float*)d_in[0];
    const int*   ei  = (const int*)d_in[1];
    const float* eps = (const float*)d_in[2];
    const float* W1  = (const float*)d_in[3];
    const float* b1  = (const float*)d_in[4];
    const float* W2  = (const float*)d_in[5];
    const float* b2  = (const float*)d_in[6];
    const float* lng = (const float*)d_in[7];
    const float* lnb = (const float*)d_in[8];
    const float* skg = (const float*)d_in[9];
    const float* skb = (const float*)d_in[10];
    float* h = (float*)d_out;

    char* ws = (char*)d_ws;
    float* agg  = (float*)ws;                                  // NPAD*128*4 = 25.6 MB
    short* zbuf = (short*)(ws + (size_t)NPAD * D * 4);         // 12.8 MB
    short* hid  = zbuf + (size_t)NPAD * D;                     // 12.8 MB
    short* wt   = hid + (size_t)NPAD * D;                      // 6*16384*2 = 192 KB
    float* vbuf = agg;                                         // alias: agg dead after prep

    const int* srcIdx = ei;
    const int* dstIdx = ei + N_EDGES;

    // h = x
    copy_f4<<<(N_NODES * 32) / 256, 256, 0, stream>>>((const f32x4*)x, (f32x4*)h);
    // transpose + bf16 weights
    prepw_kernel<<<(6 * 16384) / 256, 256, 0, stream>>>(W1, W2, wt);

    for (int l = 0; l < LAYERS; ++l) {
        hipMemsetAsync(agg, 0, (size_t)N_NODES * D * sizeof(float), stream);
        scatter_kernel<<<(N_EDGES * 32) / 256, 256, 0, stream>>>(
            srcIdx, dstIdx, (const f32x4*)h, agg);
        prep_kernel<<<(NPAD * 16) / 256, 256, 0, stream>>>(
            (const f32x4*)h, (const f32x4*)agg, eps, l, (bf16x8*)zbuf);
        gemm_kernel<true, true><<<NPAD / 64, 256, 0, stream>>>(
            zbuf, wt + l * 16384, b1 + l * D, hid, nullptr);
        gemm_kernel<false, false><<<NPAD / 64, 256, 0, stream>>>(
            hid, wt + (3 + l) * 16384, b2 + l * D, nullptr, vbuf);
        ln_res_kernel<<<(N_NODES * 32) / 256, 256, 0, stream>>>(
            (const f32x4*)vbuf, (f32x4*)h,
            lng + l * D, lnb + l * D,
            (l < LAYERS - 1) ? (skg + l * D) : nullptr,
            (l < LAYERS - 1) ? (skb + l * D) : nullptr,
            (l < LAYERS - 1) ? 1 : 0);
    }
}

// Round 2
// 398.219 us; speedup vs baseline: 8.6536x; 8.6536x over previous
//
#include <hip/hip_runtime.h>
#include <hip/hip_bf16.h>

#define N_NODES 50000
#define N_EDGES 640000
#define D 128
#define NPAD 50048   // 782 * 64
#define LAYERS 3
#define SCAN_NB 196  // ceil(50000/256)

typedef __attribute__((ext_vector_type(4))) float f32x4;
typedef __attribute__((ext_vector_type(8))) short bf16x8;
typedef __attribute__((ext_vector_type(4))) short bf16x4;

static __device__ __forceinline__ short f2bf(float f) {
    union { float f; unsigned u; } x; x.f = f;
    unsigned r = x.u + 0x7fffu + ((x.u >> 16) & 1u);  // RNE
    return (short)(r >> 16);
}

// ---------------- h = x ----------------
__global__ void copy_f4(const f32x4* __restrict__ in, f32x4* __restrict__ out) {
    int t = blockIdx.x * 256 + threadIdx.x;
    out[t] = in[t];
}

// ---------------- weights: wt[m][c][k] = bf16(W[m][k][c]) ----------------
__global__ void prepw_kernel(const float* __restrict__ W1, const float* __restrict__ W2,
                             short* __restrict__ wt) {
    int t = blockIdx.x * 256 + threadIdx.x;
    if (t >= 6 * 16384) return;
    int m = t >> 14, rem = t & 16383;
    int c = rem >> 7, k = rem & 127;
    const float* src = (m < 3) ? (W1 + m * 16384) : (W2 + (m - 3) * 16384);
    wt[m * 16384 + c * 128 + k] = f2bf(src[k * 128 + c]);
}

// ---------------- CSR build ----------------
__global__ void hist_kernel(const int* __restrict__ dst, int* __restrict__ deg) {
    int e = blockIdx.x * 256 + threadIdx.x;
    if (e < N_EDGES) atomicAdd(&deg[dst[e]], 1);
}

__global__ void scan1_kernel(const int* __restrict__ deg, int* __restrict__ rs,
                             int* __restrict__ bsum) {
    __shared__ int tmp[256];
    int i = blockIdx.x * 256 + threadIdx.x;
    int v = (i < N_NODES) ? deg[i] : 0;
    tmp[threadIdx.x] = v;
    __syncthreads();
    for (int off = 1; off < 256; off <<= 1) {
        int t = (threadIdx.x >= off) ? tmp[threadIdx.x - off] : 0;
        __syncthreads();
        tmp[threadIdx.x] += t;
        __syncthreads();
    }
    if (i < N_NODES) rs[i] = tmp[threadIdx.x] - v;  // exclusive
    if (threadIdx.x == 255) bsum[blockIdx.x] = tmp[255];
}

__global__ void scan2_kernel(int* __restrict__ bsum) {
    __shared__ int tmp[256];
    int v = (threadIdx.x < SCAN_NB) ? bsum[threadIdx.x] : 0;
    tmp[threadIdx.x] = v;
    __syncthreads();
    for (int off = 1; off < 256; off <<= 1) {
        int t = (threadIdx.x >= off) ? tmp[threadIdx.x - off] : 0;
        __syncthreads();
        tmp[threadIdx.x] += t;
        __syncthreads();
    }
    if (threadIdx.x < SCAN_NB) bsum[threadIdx.x] = tmp[threadIdx.x] - v;  // exclusive
}

__global__ void scan3_kernel(int* __restrict__ rs, const int* __restrict__ bsum) {
    int i = blockIdx.x * 256 + threadIdx.x;
    if (i < N_NODES) rs[i] += bsum[blockIdx.x];
}

__global__ void fill_kernel(const int* __restrict__ src, const int* __restrict__ dst,
                            const int* __restrict__ rs, int* __restrict__ cursor,
                            int* __restrict__ col) {
    int e = blockIdx.x * 256 + threadIdx.x;
    if (e >= N_EDGES) return;
    int d = dst[e];
    int p = atomicAdd(&cursor[d], 1);
    col[rs[d] + p] = src[e];
}

// ---------------- fused aggregate + GIN prep: z = bf16((1+eps)*h + sum_{e} h[src_e]) ----------------
__global__ __launch_bounds__(256) void agg_kernel(const f32x4* __restrict__ h,
                                                  const int* __restrict__ rs,
                                                  const int* __restrict__ deg,
                                                  const int* __restrict__ col,
                                                  const float* __restrict__ epsArr, int layer,
                                                  bf16x4* __restrict__ z) {
    int t = blockIdx.x * 256 + threadIdx.x;
    int node = t >> 5, lane = t & 31;
    if (node >= NPAD) return;
    bf16x4 o;
    if (node < N_NODES) {
        f32x4 acc = {0.f, 0.f, 0.f, 0.f};
        int start = rs[node], dg = deg[node];
        for (int base = 0; base < dg; base += 32) {
            int rem = dg - base;
            int n = rem < 32 ? rem : 32;
            int my = (lane < n) ? col[start + base + lane] : 0;
            for (int j = 0; j < n; ++j) {
                int idx = __shfl(my, j, 32);
                f32x4 v = h[(size_t)idx * 32 + lane];
                acc.x += v.x; acc.y += v.y; acc.z += v.z; acc.w += v.w;
            }
        }
        float s = 1.0f + epsArr[layer];
        f32x4 hv = h[(size_t)node * 32 + lane];
        o[0] = f2bf(fmaf(s, hv.x, acc.x));
        o[1] = f2bf(fmaf(s, hv.y, acc.y));
        o[2] = f2bf(fmaf(s, hv.z, acc.z));
        o[3] = f2bf(fmaf(s, hv.w, acc.w));
    } else {
        o = (bf16x4)(short)0;
    }
    z[(size_t)node * 32 + lane] = o;
}

// ---------------- GEMM: out = act(A @ Wt^T + bias) ----------------
template <bool RELU, bool OUTBF>
__global__ __launch_bounds__(256) void gemm_kernel(const short* __restrict__ A,
                                                   const short* __restrict__ Wt,
                                                   const float* __restrict__ bias,
                                                   short* __restrict__ obf,
                                                   float* __restrict__ of) {
    int wave = threadIdx.x >> 6, lane = threadIdx.x & 63;
    int rowBase = blockIdx.x * 64 + wave * 16;
    int r = lane & 15, kq = lane >> 4;

    const short* Ar = A + (size_t)(rowBase + r) * D + kq * 8;
    bf16x8 a0 = *(const bf16x8*)(Ar);
    bf16x8 a1 = *(const bf16x8*)(Ar + 32);
    bf16x8 a2 = *(const bf16x8*)(Ar + 64);
    bf16x8 a3 = *(const bf16x8*)(Ar + 96);

#pragma unroll
    for (int ct = 0; ct < 8; ++ct) {
        int c = ct * 16 + r;
        const short* Wc = Wt + c * D + kq * 8;
        f32x4 acc = {0.f, 0.f, 0.f, 0.f};
        acc = __builtin_amdgcn_mfma_f32_16x16x32_bf16(a0, *(const bf16x8*)(Wc), acc, 0, 0, 0);
        acc = __builtin_amdgcn_mfma_f32_16x16x32_bf16(a1, *(const bf16x8*)(Wc + 32), acc, 0, 0, 0);
        acc = __builtin_amdgcn_mfma_f32_16x16x32_bf16(a2, *(const bf16x8*)(Wc + 64), acc, 0, 0, 0);
        acc = __builtin_amdgcn_mfma_f32_16x16x32_bf16(a3, *(const bf16x8*)(Wc + 96), acc, 0, 0, 0);
        float bcol = bias[c];
        int orow = rowBase + kq * 4;
#pragma unroll
        for (int j = 0; j < 4; ++j) {
            float v = acc[j] + bcol;
            if (RELU) v = fmaxf(v, 0.0f);
            int rr = orow + j;
            if (rr < N_NODES) {
                if (OUTBF) obf[(size_t)rr * D + c] = f2bf(v);
                else       of[(size_t)rr * D + c] = v;
            }
        }
    }
}

// ---------------- LN (+ skip LN + relu) + residual ----------------
__global__ void ln_res_kernel(const f32x4* __restrict__ v, f32x4* __restrict__ h,
                              const float* __restrict__ g1, const float* __restrict__ b1,
                              const float* __restrict__ g2, const float* __restrict__ b2,
                              int hasSkip) {
    int t = blockIdx.x * 256 + threadIdx.x;
    int row = t >> 5, lane = t & 31;
    if (row >= N_NODES) return;
    f32x4 x = v[(size_t)row * 32 + lane];
    float s = x.x + x.y + x.z + x.w;
    float q = x.x * x.x + x.y * x.y + x.z * x.z + x.w * x.w;
#pragma unroll
    for (int m = 1; m < 32; m <<= 1) {
        s += __shfl_xor(s, m, 64);
        q += __shfl_xor(q, m, 64);
    }
    float mu = s * (1.0f / D);
    float rs = rsqrtf(q * (1.0f / D) - mu * mu + 1e-5f);
    int c = lane * 4;
    f32x4 ga = *(const f32x4*)(g1 + c);
    f32x4 ba = *(const f32x4*)(b1 + c);
    f32x4 y;
    y.x = (x.x - mu) * rs * ga.x + ba.x;
    y.y = (x.y - mu) * rs * ga.y + ba.y;
    y.z = (x.z - mu) * rs * ga.z + ba.z;
    y.w = (x.w - mu) * rs * ga.w + ba.w;
    if (hasSkip) {
        float s2 = y.x + y.y + y.z + y.w;
        float q2 = y.x * y.x + y.y * y.y + y.z * y.z + y.w * y.w;
#pragma unroll
        for (int m = 1; m < 32; m <<= 1) {
            s2 += __shfl_xor(s2, m, 64);
            q2 += __shfl_xor(q2, m, 64);
        }
        float mu2 = s2 * (1.0f / D);
        float rs2 = rsqrtf(q2 * (1.0f / D) - mu2 * mu2 + 1e-5f);
        f32x4 gb = *(const f32x4*)(g2 + c);
        f32x4 bb = *(const f32x4*)(b2 + c);
        y.x = fmaxf((y.x - mu2) * rs2 * gb.x + bb.x, 0.0f);
        y.y = fmaxf((y.y - mu2) * rs2 * gb.y + bb.y, 0.0f);
        y.z = fmaxf((y.z - mu2) * rs2 * gb.z + bb.z, 0.0f);
        y.w = fmaxf((y.w - mu2) * rs2 * gb.w + bb.w, 0.0f);
    }
    f32x4 ho = h[(size_t)row * 32 + lane];
    ho.x += y.x; ho.y += y.y; ho.z += y.z; ho.w += y.w;
    h[(size_t)row * 32 + lane] = ho;
}

extern "C" void kernel_launch(void* const* d_in, const int* in_sizes, int n_in,
                              void* d_out, int out_size, void* d_ws, size_t ws_size,
                              hipStream_t stream) {
    const float* x   = (const float*)d_in[0];
    const int*   ei  = (const int*)d_in[1];
    const float* eps = (const float*)d_in[2];
    const float* W1  = (const float*)d_in[3];
    const float* b1  = (const float*)d_in[4];
    const float* W2  = (const float*)d_in[5];
    const float* b2  = (const float*)d_in[6];
    const float* lng = (const float*)d_in[7];
    const float* lnb = (const float*)d_in[8];
    const float* skg = (const float*)d_in[9];
    const float* skb = (const float*)d_in[10];
    float* h = (float*)d_out;

    char* ws = (char*)d_ws;
    // vbuf (f32 N_NODES*128 = 25.6 MB) aliases zbuf (bf16 NPAD*128 = 12.8 MB):
    // zbuf is dead by the time gemm2 writes vbuf.
    float* vbuf = (float*)ws;
    short* zbuf = (short*)ws;
    short* hid  = (short*)(ws + 25600000);           // 12,812,288 B
    short* wt   = (short*)(ws + 38412288);           //    196,608 B
    int*   rs   = (int*)  (ws + 38608896);           //    200,192 B
    int*   deg  = (int*)  (ws + 38809088);           //    200,192 B
    int*   cur  = (int*)  (ws + 39009280);           //    200,192 B
    int*   col  = (int*)  (ws + 39209472);           //  2,560,000 B
    int*   bsum = (int*)  (ws + 41769472);           //      1,024 B

    const int* srcIdx = ei;
    const int* dstIdx = ei + N_EDGES;

    copy_f4<<<(N_NODES * 32) / 256, 256, 0, stream>>>((const f32x4*)x, (f32x4*)h);
    prepw_kernel<<<(6 * 16384) / 256, 256, 0, stream>>>(W1, W2, wt);

    // CSR build (deg and cur are contiguous -> one memset)
    hipMemsetAsync(deg, 0, 2 * 200192, stream);
    hist_kernel<<<(N_EDGES + 255) / 256, 256, 0, stream>>>(dstIdx, deg);
    scan1_kernel<<<SCAN_NB, 256, 0, stream>>>(deg, rs, bsum);
    scan2_kernel<<<1, 256, 0, stream>>>(bsum);
    scan3_kernel<<<SCAN_NB, 256, 0, stream>>>(rs, bsum);
    fill_kernel<<<(N_EDGES + 255) / 256, 256, 0, stream>>>(srcIdx, dstIdx, rs, cur, col);

    for (int l = 0; l < LAYERS; ++l) {
        agg_kernel<<<(NPAD * 32) / 256, 256, 0, stream>>>(
            (const f32x4*)h, rs, deg, col, eps, l, (bf16x4*)zbuf);
        gemm_kernel<true, true><<<NPAD / 64, 256, 0, stream>>>(
            zbuf, wt + l * 16384, b1 + l * D, hid, nullptr);
        gemm_kernel<false, false><<<NPAD / 64, 256, 0, stream>>>(
            hid, wt + (3 + l) * 16384, b2 + l * D, nullptr, vbuf);
        ln_res_kernel<<<(N_NODES * 32) / 256, 256, 0, stream>>>(
            (const f32x4*)vbuf, (f32x4*)h,
            lng + l * D, lnb + l * D,
            (l < LAYERS - 1) ? (skg + l * D) : nullptr,
            (l < LAYERS - 1) ? (skb + l * D) : nullptr,
            (l < LAYERS - 1) ? 1 : 0);
    }
}

// Round 3
// 328.085 us; speedup vs baseline: 10.5034x; 1.2138x over previous
//
#include <hip/hip_runtime.h>
#include <hip/hip_bf16.h>

#define N_NODES 50000
#define N_EDGES 640000
#define D 128
#define NPAD 50048   // 782 * 64
#define LAYERS 3
#define SCAN_NB 196  // ceil(50000/256)

typedef __attribute__((ext_vector_type(4))) float f32x4;
typedef __attribute__((ext_vector_type(8))) short bf16x8;
typedef __attribute__((ext_vector_type(4))) short bf16x4;

static __device__ __forceinline__ short f2bf(float f) {
    union { float f; unsigned u; } x; x.f = f;
    unsigned r = x.u + 0x7fffu + ((x.u >> 16) & 1u);  // RNE
    return (short)(r >> 16);
}
static __device__ __forceinline__ float bf2f(short s) {
    union { unsigned u; float f; } x; x.u = ((unsigned)(unsigned short)s) << 16;
    return x.f;
}

// ---------------- h = x (f32) and hb = bf16(x) ----------------
__global__ void init_kernel(const f32x4* __restrict__ in, f32x4* __restrict__ h,
                            bf16x4* __restrict__ hb) {
    int t = blockIdx.x * 256 + threadIdx.x;
    f32x4 v = in[t];
    h[t] = v;
    bf16x4 p; p[0] = f2bf(v.x); p[1] = f2bf(v.y); p[2] = f2bf(v.z); p[3] = f2bf(v.w);
    hb[t] = p;
}

// ---------------- weights: wt[m][c][k] = bf16(W[m][k][c]) ----------------
__global__ void prepw_kernel(const float* __restrict__ W1, const float* __restrict__ W2,
                             short* __restrict__ wt) {
    int t = blockIdx.x * 256 + threadIdx.x;
    if (t >= 6 * 16384) return;
    int m = t >> 14, rem = t & 16383;
    int c = rem >> 7, k = rem & 127;
    const float* src = (m < 3) ? (W1 + m * 16384) : (W2 + (m - 3) * 16384);
    wt[m * 16384 + c * 128 + k] = f2bf(src[k * 128 + c]);
}

// ---------------- CSR build ----------------
__global__ void hist_kernel(const int* __restrict__ dst, int* __restrict__ deg) {
    int e = blockIdx.x * 256 + threadIdx.x;
    if (e < N_EDGES) atomicAdd(&deg[dst[e]], 1);
}

__global__ void scan1_kernel(const int* __restrict__ deg, int* __restrict__ rs,
                             int* __restrict__ bsum) {
    __shared__ int tmp[256];
    int i = blockIdx.x * 256 + threadIdx.x;
    int v = (i < N_NODES) ? deg[i] : 0;
    tmp[threadIdx.x] = v;
    __syncthreads();
    for (int off = 1; off < 256; off <<= 1) {
        int t = (threadIdx.x >= off) ? tmp[threadIdx.x - off] : 0;
        __syncthreads();
        tmp[threadIdx.x] += t;
        __syncthreads();
    }
    if (i < N_NODES) rs[i] = tmp[threadIdx.x] - v;  // exclusive
    if (threadIdx.x == 255) bsum[blockIdx.x] = tmp[255];
}

__global__ void scan2_kernel(int* __restrict__ bsum) {
    __shared__ int tmp[256];
    int v = (threadIdx.x < SCAN_NB) ? bsum[threadIdx.x] : 0;
    tmp[threadIdx.x] = v;
    __syncthreads();
    for (int off = 1; off < 256; off <<= 1) {
        int t = (threadIdx.x >= off) ? tmp[threadIdx.x - off] : 0;
        __syncthreads();
        tmp[threadIdx.x] += t;
        __syncthreads();
    }
    if (threadIdx.x < SCAN_NB) bsum[threadIdx.x] = tmp[threadIdx.x] - v;  // exclusive
}

__global__ void scan3_kernel(int* __restrict__ rs, const int* __restrict__ bsum) {
    int i = blockIdx.x * 256 + threadIdx.x;
    if (i < N_NODES) rs[i] += bsum[blockIdx.x];
}

__global__ void fill_kernel(const int* __restrict__ src, const int* __restrict__ dst,
                            const int* __restrict__ rs, int* __restrict__ cursor,
                            int* __restrict__ col) {
    int e = blockIdx.x * 256 + threadIdx.x;
    if (e >= N_EDGES) return;
    int d = dst[e];
    int p = atomicAdd(&cursor[d], 1);
    col[rs[d] + p] = src[e];
}

// ---------------- fused aggregate + GIN prep: z = bf16((1+eps)*h_f32 + sum hb[src]) --------
__global__ __launch_bounds__(256) void agg_kernel(const f32x4* __restrict__ h,
                                                  const bf16x4* __restrict__ hb,
                                                  const int* __restrict__ rs,
                                                  const int* __restrict__ deg,
                                                  const int* __restrict__ col,
                                                  const float* __restrict__ epsArr, int layer,
                                                  bf16x4* __restrict__ z) {
    int t = blockIdx.x * 256 + threadIdx.x;
    int node = t >> 5, lane = t & 31;
    if (node >= NPAD) return;
    bf16x4 o;
    if (node < N_NODES) {
        f32x4 acc = {0.f, 0.f, 0.f, 0.f};
        int start = rs[node], dg = deg[node];
        for (int base = 0; base < dg; base += 32) {
            int rem = dg - base;
            int n = rem < 32 ? rem : 32;
            int my = (lane < n) ? col[start + base + lane] : 0;
            for (int j = 0; j < n; ++j) {
                int idx = __shfl(my, j, 32);
                bf16x4 v = hb[(size_t)idx * 32 + lane];
                acc.x += bf2f(v[0]); acc.y += bf2f(v[1]);
                acc.z += bf2f(v[2]); acc.w += bf2f(v[3]);
            }
        }
        float s = 1.0f + epsArr[layer];
        f32x4 hv = h[(size_t)node * 32 + lane];
        o[0] = f2bf(fmaf(s, hv.x, acc.x));
        o[1] = f2bf(fmaf(s, hv.y, acc.y));
        o[2] = f2bf(fmaf(s, hv.z, acc.z));
        o[3] = f2bf(fmaf(s, hv.w, acc.w));
    } else {
        o = (bf16x4)(short)0;
    }
    z[(size_t)node * 32 + lane] = o;
}

// ---------------- fused MLP + LN(+skipLN+ReLU) + residual, updates h (and hb) ----------------
// Swapped-operand MFMA: lane holds 32 features of ONE node row -> LN reduce = shfl_xor(16,32).
template <bool LAST>
__global__ __launch_bounds__(256) void mlp_kernel(const short* __restrict__ Z,
                                                  const short* __restrict__ Wt1,
                                                  const float* __restrict__ B1,
                                                  const short* __restrict__ Wt2,
                                                  const float* __restrict__ B2,
                                                  const float* __restrict__ G1,
                                                  const float* __restrict__ Bt1,
                                                  const float* __restrict__ G2,
                                                  const float* __restrict__ Bt2,
                                                  float* __restrict__ H,
                                                  short* __restrict__ HB) {
    __shared__ short hidS[64 * 128];  // 16 KB, XOR-swizzled rows
    int wave = threadIdx.x >> 6, lane = threadIdx.x & 63;
    int r = lane & 15, kq = lane >> 4;
    int lrow = wave * 16 + r;                 // 0..63 local row
    int row = blockIdx.x * 64 + lrow;         // global node row
    int swz = (lrow & 7) << 4;
    char* lbase = (char*)hidS;

    // z B-fragments (B[k][col]: col = node row, k contiguous 8)
    const short* Zr = Z + (size_t)row * D + kq * 8;
    bf16x8 zb0 = *(const bf16x8*)(Zr);
    bf16x8 zb1 = *(const bf16x8*)(Zr + 32);
    bf16x8 zb2 = *(const bf16x8*)(Zr + 64);
    bf16x8 zb3 = *(const bf16x8*)(Zr + 96);

    // ---- GEMM1 (swapped): hid[row][f] , f = ct*16 + kq*4 + j ----
#pragma unroll
    for (int ct = 0; ct < 8; ++ct) {
        const short* Wc = Wt1 + (ct * 16 + r) * D + kq * 8;
        f32x4 acc = {0.f, 0.f, 0.f, 0.f};
        acc = __builtin_amdgcn_mfma_f32_16x16x32_bf16(*(const bf16x8*)(Wc),      zb0, acc, 0, 0, 0);
        acc = __builtin_amdgcn_mfma_f32_16x16x32_bf16(*(const bf16x8*)(Wc + 32), zb1, acc, 0, 0, 0);
        acc = __builtin_amdgcn_mfma_f32_16x16x32_bf16(*(const bf16x8*)(Wc + 64), zb2, acc, 0, 0, 0);
        acc = __builtin_amdgcn_mfma_f32_16x16x32_bf16(*(const bf16x8*)(Wc + 96), zb3, acc, 0, 0, 0);
        f32x4 bias = *(const f32x4*)(B1 + ct * 16 + kq * 4);
        bf16x4 p;
        p[0] = f2bf(fmaxf(acc[0] + bias.x, 0.0f));
        p[1] = f2bf(fmaxf(acc[1] + bias.y, 0.0f));
        p[2] = f2bf(fmaxf(acc[2] + bias.z, 0.0f));
        p[3] = f2bf(fmaxf(acc[3] + bias.w, 0.0f));
        *(bf16x4*)(lbase + ((lrow * 256 + ct * 32 + kq * 8) ^ swz)) = p;
    }
    __syncthreads();

    // ---- hid B-fragments from LDS ----
    bf16x8 hb0 = *(const bf16x8*)(lbase + ((lrow * 256 + 0 * 64 + kq * 16) ^ swz));
    bf16x8 hb1 = *(const bf16x8*)(lbase + ((lrow * 256 + 1 * 64 + kq * 16) ^ swz));
    bf16x8 hb2 = *(const bf16x8*)(lbase + ((lrow * 256 + 2 * 64 + kq * 16) ^ swz));
    bf16x8 hb3 = *(const bf16x8*)(lbase + ((lrow * 256 + 3 * 64 + kq * 16) ^ swz));

    // ---- GEMM2 (swapped) + bias ----
    f32x4 o[8];
#pragma unroll
    for (int ct = 0; ct < 8; ++ct) {
        const short* Wc = Wt2 + (ct * 16 + r) * D + kq * 8;
        f32x4 acc = {0.f, 0.f, 0.f, 0.f};
        acc = __builtin_amdgcn_mfma_f32_16x16x32_bf16(*(const bf16x8*)(Wc),      hb0, acc, 0, 0, 0);
        acc = __builtin_amdgcn_mfma_f32_16x16x32_bf16(*(const bf16x8*)(Wc + 32), hb1, acc, 0, 0, 0);
        acc = __builtin_amdgcn_mfma_f32_16x16x32_bf16(*(const bf16x8*)(Wc + 64), hb2, acc, 0, 0, 0);
        acc = __builtin_amdgcn_mfma_f32_16x16x32_bf16(*(const bf16x8*)(Wc + 96), hb3, acc, 0, 0, 0);
        f32x4 bias = *(const f32x4*)(B2 + ct * 16 + kq * 4);
        o[ct] = acc + bias;
    }

    // ---- LayerNorm over the row (128 vals: 32 here + 3 sibling lanes) ----
    float s = 0.f, q = 0.f;
#pragma unroll
    for (int ct = 0; ct < 8; ++ct) {
        s += o[ct].x + o[ct].y + o[ct].z + o[ct].w;
        q += o[ct].x * o[ct].x + o[ct].y * o[ct].y + o[ct].z * o[ct].z + o[ct].w * o[ct].w;
    }
    s += __shfl_xor(s, 16, 64); q += __shfl_xor(q, 16, 64);
    s += __shfl_xor(s, 32, 64); q += __shfl_xor(q, 32, 64);
    float mu = s * (1.0f / D);
    float rstd = rsqrtf(q * (1.0f / D) - mu * mu + 1e-5f);
#pragma unroll
    for (int ct = 0; ct < 8; ++ct) {
        f32x4 g = *(const f32x4*)(G1 + ct * 16 + kq * 4);
        f32x4 b = *(const f32x4*)(Bt1 + ct * 16 + kq * 4);
        o[ct] = (o[ct] - mu) * rstd * g + b;
    }

    if (!LAST) {
        // skip-path LN + ReLU
        float s2 = 0.f, q2 = 0.f;
#pragma unroll
        for (int ct = 0; ct < 8; ++ct) {
            s2 += o[ct].x + o[ct].y + o[ct].z + o[ct].w;
            q2 += o[ct].x * o[ct].x + o[ct].y * o[ct].y + o[ct].z * o[ct].z + o[ct].w * o[ct].w;
        }
        s2 += __shfl_xor(s2, 16, 64); q2 += __shfl_xor(q2, 16, 64);
        s2 += __shfl_xor(s2, 32, 64); q2 += __shfl_xor(q2, 32, 64);
        float mu2 = s2 * (1.0f / D);
        float rstd2 = rsqrtf(q2 * (1.0f / D) - mu2 * mu2 + 1e-5f);
#pragma unroll
        for (int ct = 0; ct < 8; ++ct) {
            f32x4 g = *(const f32x4*)(G2 + ct * 16 + kq * 4);
            f32x4 b = *(const f32x4*)(Bt2 + ct * 16 + kq * 4);
            f32x4 y = (o[ct] - mu2) * rstd2 * g + b;
            y.x = fmaxf(y.x, 0.f); y.y = fmaxf(y.y, 0.f);
            y.z = fmaxf(y.z, 0.f); y.w = fmaxf(y.w, 0.f);
            o[ct] = y;
        }
    }

    // ---- residual + store h (and hb for next layer's gather) ----
    if (row < N_NODES) {
#pragma unroll
        for (int ct = 0; ct < 8; ++ct) {
            size_t off = (size_t)row * D + ct * 16 + kq * 4;
            f32x4 hv = *(const f32x4*)(H + off);
            hv += o[ct];
            *(f32x4*)(H + off) = hv;
            if (!LAST) {
                bf16x4 p;
                p[0] = f2bf(hv.x); p[1] = f2bf(hv.y); p[2] = f2bf(hv.z); p[3] = f2bf(hv.w);
                *(bf16x4*)(HB + off) = p;
            }
        }
    }
}

extern "C" void kernel_launch(void* const* d_in, const int* in_sizes, int n_in,
                              void* d_out, int out_size, void* d_ws, size_t ws_size,
                              hipStream_t stream) {
    const float* x   = (const float*)d_in[0];
    const int*   ei  = (const int*)d_in[1];
    const float* eps = (const float*)d_in[2];
    const float* W1  = (const float*)d_in[3];
    const float* b1  = (const float*)d_in[4];
    const float* W2  = (const float*)d_in[5];
    const float* b2  = (const float*)d_in[6];
    const float* lng = (const float*)d_in[7];
    const float* lnb = (const float*)d_in[8];
    const float* skg = (const float*)d_in[9];
    const float* skb = (const float*)d_in[10];
    float* h = (float*)d_out;

    char* ws = (char*)d_ws;
    short* zbuf = (short*)ws;                         // 12,812,288 B
    short* hbb  = (short*)(ws + 12812288);            // 12,812,288 B
    short* wt   = (short*)(ws + 25624576);            //    196,608 B
    int*   rs   = (int*)  (ws + 25821184);            //    200,192 B
    int*   deg  = (int*)  (ws + 26021376);            //    200,192 B
    int*   cur  = (int*)  (ws + 26221568);            //    200,192 B
    int*   col  = (int*)  (ws + 26421760);            //  2,560,000 B
    int*   bsum = (int*)  (ws + 28981760);            //      1,024 B

    const int* srcIdx = ei;
    const int* dstIdx = ei + N_EDGES;

    init_kernel<<<(N_NODES * 32) / 256, 256, 0, stream>>>(
        (const f32x4*)x, (f32x4*)h, (bf16x4*)hbb);
    prepw_kernel<<<(6 * 16384) / 256, 256, 0, stream>>>(W1, W2, wt);

    hipMemsetAsync(deg, 0, 2 * 200192, stream);  // deg + cur contiguous
    hist_kernel<<<(N_EDGES + 255) / 256, 256, 0, stream>>>(dstIdx, deg);
    scan1_kernel<<<SCAN_NB, 256, 0, stream>>>(deg, rs, bsum);
    scan2_kernel<<<1, 256, 0, stream>>>(bsum);
    scan3_kernel<<<SCAN_NB, 256, 0, stream>>>(rs, bsum);
    fill_kernel<<<(N_EDGES + 255) / 256, 256, 0, stream>>>(srcIdx, dstIdx, rs, cur, col);

    for (int l = 0; l < LAYERS; ++l) {
        agg_kernel<<<(NPAD * 32) / 256, 256, 0, stream>>>(
            (const f32x4*)h, (const bf16x4*)hbb, rs, deg, col, eps, l, (bf16x4*)zbuf);
        if (l < LAYERS - 1) {
            mlp_kernel<false><<<NPAD / 64, 256, 0, stream>>>(
                zbuf, wt + l * 16384, b1 + l * D, wt + (3 + l) * 16384, b2 + l * D,
                lng + l * D, lnb + l * D, skg + l * D, skb + l * D, h, hbb);
        } else {
            mlp_kernel<true><<<NPAD / 64, 256, 0, stream>>>(
                zbuf, wt + l * 16384, b1 + l * D, wt + (3 + l) * 16384, b2 + l * D,
                lng + l * D, lnb + l * D, nullptr, nullptr, h, nullptr);
        }
    }
}

// Round 4
// 297.872 us; speedup vs baseline: 11.5688x; 1.1014x over previous
//
#include <hip/hip_runtime.h>
#include <hip/hip_bf16.h>

#define N_NODES 50000
#define N_EDGES 640000
#define D 128
#define NPAD 50048   // 782 * 64
#define LAYERS 3
#define SCAN_NB 196  // ceil(50000/256)

typedef __attribute__((ext_vector_type(4))) float f32x4;
typedef __attribute__((ext_vector_type(8))) short bf16x8;
typedef __attribute__((ext_vector_type(4))) short bf16x4;

static __device__ __forceinline__ short f2bf(float f) {
    union { float f; unsigned u; } x; x.f = f;
    unsigned r = x.u + 0x7fffu + ((x.u >> 16) & 1u);  // RNE
    return (short)(r >> 16);
}
static __device__ __forceinline__ float bf2f(short s) {
    union { unsigned u; float f; } x; x.u = ((unsigned)(unsigned short)s) << 16;
    return x.f;
}

// ---------------- hb = bf16(x) ----------------
__global__ void init_kernel(const f32x4* __restrict__ in, bf16x4* __restrict__ hb) {
    int t = blockIdx.x * 256 + threadIdx.x;
    f32x4 v = in[t];
    bf16x4 p; p[0] = f2bf(v.x); p[1] = f2bf(v.y); p[2] = f2bf(v.z); p[3] = f2bf(v.w);
    hb[t] = p;
}

// ---------------- weights: wt[m][c][k] = bf16(W[m][k][c]) ----------------
__global__ void prepw_kernel(const float* __restrict__ W1, const float* __restrict__ W2,
                             short* __restrict__ wt) {
    int t = blockIdx.x * 256 + threadIdx.x;
    if (t >= 6 * 16384) return;
    int m = t >> 14, rem = t & 16383;
    int c = rem >> 7, k = rem & 127;
    const float* src = (m < 3) ? (W1 + m * 16384) : (W2 + (m - 3) * 16384);
    wt[m * 16384 + c * 128 + k] = f2bf(src[k * 128 + c]);
}

// ---------------- CSR build ----------------
__global__ void hist_kernel(const int* __restrict__ dst, int* __restrict__ deg) {
    int e = blockIdx.x * 256 + threadIdx.x;
    if (e < N_EDGES) atomicAdd(&deg[dst[e]], 1);
}

__global__ void scan1_kernel(const int* __restrict__ deg, int* __restrict__ rs,
                             int* __restrict__ bsum) {
    __shared__ int tmp[256];
    int i = blockIdx.x * 256 + threadIdx.x;
    int v = (i < N_NODES) ? deg[i] : 0;
    tmp[threadIdx.x] = v;
    __syncthreads();
    for (int off = 1; off < 256; off <<= 1) {
        int t = (threadIdx.x >= off) ? tmp[threadIdx.x - off] : 0;
        __syncthreads();
        tmp[threadIdx.x] += t;
        __syncthreads();
    }
    if (i < N_NODES) rs[i] = tmp[threadIdx.x] - v;  // exclusive
    if (threadIdx.x == 255) bsum[blockIdx.x] = tmp[255];
}

__global__ void scan2_kernel(int* __restrict__ bsum) {
    __shared__ int tmp[256];
    int v = (threadIdx.x < SCAN_NB) ? bsum[threadIdx.x] : 0;
    tmp[threadIdx.x] = v;
    __syncthreads();
    for (int off = 1; off < 256; off <<= 1) {
        int t = (threadIdx.x >= off) ? tmp[threadIdx.x - off] : 0;
        __syncthreads();
        tmp[threadIdx.x] += t;
        __syncthreads();
    }
    if (threadIdx.x < SCAN_NB) bsum[threadIdx.x] = tmp[threadIdx.x] - v;  // exclusive
}

__global__ void scan3_kernel(int* __restrict__ rs, const int* __restrict__ bsum) {
    int i = blockIdx.x * 256 + threadIdx.x;
    if (i < N_NODES) rs[i] += bsum[blockIdx.x];
}

__global__ void fill_kernel(const int* __restrict__ src, const int* __restrict__ dst,
                            const int* __restrict__ rs, int* __restrict__ cursor,
                            int* __restrict__ col) {
    int e = blockIdx.x * 256 + threadIdx.x;
    if (e >= N_EDGES) return;
    int d = dst[e];
    int p = atomicAdd(&cursor[d], 1);
    col[rs[d] + p] = src[e];
}

// ---------------- fused aggregate + GIN prep: z = bf16((1+eps)*hb + sum hb[src]) --------
// 16 lanes per node, bf16x8 per lane. Neighbor index loads: all 16 lanes read the
// same address (HW broadcast), 4 independent row-gathers in flight, no shuffles.
__global__ __launch_bounds__(256) void agg_kernel(const bf16x8* __restrict__ hb,
                                                  const int* __restrict__ rs,
                                                  const int* __restrict__ deg,
                                                  const int* __restrict__ col,
                                                  const float* __restrict__ epsArr, int layer,
                                                  bf16x8* __restrict__ z) {
    int t = blockIdx.x * 256 + threadIdx.x;
    int node = t >> 4, lane = t & 15;
    if (node >= NPAD) return;
    bf16x8 o;
    if (node < N_NODES) {
        float acc[8] = {0.f, 0.f, 0.f, 0.f, 0.f, 0.f, 0.f, 0.f};
        int start = rs[node], dg = deg[node];
        const int* cp = col + start;
        int base = 0;
        for (; base + 4 <= dg; base += 4) {
            int c0 = cp[base], c1 = cp[base + 1], c2 = cp[base + 2], c3 = cp[base + 3];
            bf16x8 v0 = hb[(size_t)c0 * 16 + lane];
            bf16x8 v1 = hb[(size_t)c1 * 16 + lane];
            bf16x8 v2 = hb[(size_t)c2 * 16 + lane];
            bf16x8 v3 = hb[(size_t)c3 * 16 + lane];
#pragma unroll
            for (int e = 0; e < 8; ++e)
                acc[e] += (bf2f(v0[e]) + bf2f(v1[e])) + (bf2f(v2[e]) + bf2f(v3[e]));
        }
        for (; base < dg; ++base) {
            bf16x8 v = hb[(size_t)cp[base] * 16 + lane];
#pragma unroll
            for (int e = 0; e < 8; ++e) acc[e] += bf2f(v[e]);
        }
        float s = 1.0f + epsArr[layer];
        bf16x8 hv = hb[(size_t)node * 16 + lane];
#pragma unroll
        for (int e = 0; e < 8; ++e) o[e] = f2bf(fmaf(s, bf2f(hv[e]), acc[e]));
    } else {
        o = (bf16x8)(short)0;
    }
    z[(size_t)node * 16 + lane] = o;
}

// ---------------- fused MLP + LN(+skipLN+ReLU) + residual ----------------
// Swapped-operand MFMA: lane holds 32 features of ONE node row.
// All 32 W fragments per GEMM preloaded into registers (static-index array) for ILP.
template <bool LAST>
__global__ __launch_bounds__(256, 2) void mlp_kernel(const short* __restrict__ Z,
                                                     const short* __restrict__ Wt1,
                                                     const float* __restrict__ B1,
                                                     const short* __restrict__ Wt2,
                                                     const float* __restrict__ B2,
                                                     const float* __restrict__ G1,
                                                     const float* __restrict__ Bt1,
                                                     const float* __restrict__ G2,
                                                     const float* __restrict__ Bt2,
                                                     const float* __restrict__ RS,
                                                     float* __restrict__ H,
                                                     short* __restrict__ HB) {
    __shared__ short hidS[64 * 128];  // 16 KB, XOR-swizzled rows
    int wave = threadIdx.x >> 6, lane = threadIdx.x & 63;
    int r = lane & 15, kq = lane >> 4;
    int lrow = wave * 16 + r;
    int row = blockIdx.x * 64 + lrow;
    int swz = (lrow & 7) << 4;
    char* lbase = (char*)hidS;

    // ---- preload all W1 fragments (32 x 16B, independent loads) ----
    const short* Wb1 = Wt1 + r * D + kq * 8;
    bf16x8 w[8][4];
#pragma unroll
    for (int ct = 0; ct < 8; ++ct) {
#pragma unroll
        for (int k = 0; k < 4; ++k)
            w[ct][k] = *(const bf16x8*)(Wb1 + ct * 16 * D + k * 32);
    }

    // ---- z B-fragments ----
    const short* Zr = Z + (size_t)row * D + kq * 8;
    bf16x8 zb0 = *(const bf16x8*)(Zr);
    bf16x8 zb1 = *(const bf16x8*)(Zr + 32);
    bf16x8 zb2 = *(const bf16x8*)(Zr + 64);
    bf16x8 zb3 = *(const bf16x8*)(Zr + 96);

    // ---- GEMM1 + bias + ReLU -> LDS (bf16) ----
#pragma unroll
    for (int ct = 0; ct < 8; ++ct) {
        f32x4 acc = {0.f, 0.f, 0.f, 0.f};
        acc = __builtin_amdgcn_mfma_f32_16x16x32_bf16(w[ct][0], zb0, acc, 0, 0, 0);
        acc = __builtin_amdgcn_mfma_f32_16x16x32_bf16(w[ct][1], zb1, acc, 0, 0, 0);
        acc = __builtin_amdgcn_mfma_f32_16x16x32_bf16(w[ct][2], zb2, acc, 0, 0, 0);
        acc = __builtin_amdgcn_mfma_f32_16x16x32_bf16(w[ct][3], zb3, acc, 0, 0, 0);
        f32x4 bias = *(const f32x4*)(B1 + ct * 16 + kq * 4);
        bf16x4 p;
        p[0] = f2bf(fmaxf(acc[0] + bias.x, 0.0f));
        p[1] = f2bf(fmaxf(acc[1] + bias.y, 0.0f));
        p[2] = f2bf(fmaxf(acc[2] + bias.z, 0.0f));
        p[3] = f2bf(fmaxf(acc[3] + bias.w, 0.0f));
        *(bf16x4*)(lbase + ((lrow * 256 + ct * 32 + kq * 8) ^ swz)) = p;
    }
    __syncthreads();

    // ---- preload all W2 fragments (overlaps with LDS reads below) ----
    const short* Wb2 = Wt2 + r * D + kq * 8;
#pragma unroll
    for (int ct = 0; ct < 8; ++ct) {
#pragma unroll
        for (int k = 0; k < 4; ++k)
            w[ct][k] = *(const bf16x8*)(Wb2 + ct * 16 * D + k * 32);
    }

    // ---- hid B-fragments from LDS ----
    bf16x8 hb0 = *(const bf16x8*)(lbase + ((lrow * 256 + 0 * 64 + kq * 16) ^ swz));
    bf16x8 hb1 = *(const bf16x8*)(lbase + ((lrow * 256 + 1 * 64 + kq * 16) ^ swz));
    bf16x8 hb2 = *(const bf16x8*)(lbase + ((lrow * 256 + 2 * 64 + kq * 16) ^ swz));
    bf16x8 hb3 = *(const bf16x8*)(lbase + ((lrow * 256 + 3 * 64 + kq * 16) ^ swz));

    // ---- GEMM2 + bias ----
    f32x4 o[8];
#pragma unroll
    for (int ct = 0; ct < 8; ++ct) {
        f32x4 acc = {0.f, 0.f, 0.f, 0.f};
        acc = __builtin_amdgcn_mfma_f32_16x16x32_bf16(w[ct][0], hb0, acc, 0, 0, 0);
        acc = __builtin_amdgcn_mfma_f32_16x16x32_bf16(w[ct][1], hb1, acc, 0, 0, 0);
        acc = __builtin_amdgcn_mfma_f32_16x16x32_bf16(w[ct][2], hb2, acc, 0, 0, 0);
        acc = __builtin_amdgcn_mfma_f32_16x16x32_bf16(w[ct][3], hb3, acc, 0, 0, 0);
        f32x4 bias = *(const f32x4*)(B2 + ct * 16 + kq * 4);
        o[ct] = acc + bias;
    }

    // ---- LayerNorm over the row ----
    float s = 0.f, q = 0.f;
#pragma unroll
    for (int ct = 0; ct < 8; ++ct) {
        s += o[ct].x + o[ct].y + o[ct].z + o[ct].w;
        q += o[ct].x * o[ct].x + o[ct].y * o[ct].y + o[ct].z * o[ct].z + o[ct].w * o[ct].w;
    }
    s += __shfl_xor(s, 16, 64); q += __shfl_xor(q, 16, 64);
    s += __shfl_xor(s, 32, 64); q += __shfl_xor(q, 32, 64);
    float mu = s * (1.0f / D);
    float rstd = rsqrtf(q * (1.0f / D) - mu * mu + 1e-5f);
#pragma unroll
    for (int ct = 0; ct < 8; ++ct) {
        f32x4 g = *(const f32x4*)(G1 + ct * 16 + kq * 4);
        f32x4 b = *(const f32x4*)(Bt1 + ct * 16 + kq * 4);
        o[ct] = (o[ct] - mu) * rstd * g + b;
    }

    if (!LAST) {
        float s2 = 0.f, q2 = 0.f;
#pragma unroll
        for (int ct = 0; ct < 8; ++ct) {
            s2 += o[ct].x + o[ct].y + o[ct].z + o[ct].w;
            q2 += o[ct].x * o[ct].x + o[ct].y * o[ct].y + o[ct].z * o[ct].z + o[ct].w * o[ct].w;
        }
        s2 += __shfl_xor(s2, 16, 64); q2 += __shfl_xor(q2, 16, 64);
        s2 += __shfl_xor(s2, 32, 64); q2 += __shfl_xor(q2, 32, 64);
        float mu2 = s2 * (1.0f / D);
        float rstd2 = rsqrtf(q2 * (1.0f / D) - mu2 * mu2 + 1e-5f);
#pragma unroll
        for (int ct = 0; ct < 8; ++ct) {
            f32x4 g = *(const f32x4*)(G2 + ct * 16 + kq * 4);
            f32x4 b = *(const f32x4*)(Bt2 + ct * 16 + kq * 4);
            f32x4 y = (o[ct] - mu2) * rstd2 * g + b;
            y.x = fmaxf(y.x, 0.f); y.y = fmaxf(y.y, 0.f);
            y.z = fmaxf(y.z, 0.f); y.w = fmaxf(y.w, 0.f);
            o[ct] = y;
        }
    }

    // ---- residual + store ----
    if (row < N_NODES) {
#pragma unroll
        for (int ct = 0; ct < 8; ++ct) {
            size_t off = (size_t)row * D + ct * 16 + kq * 4;
            f32x4 hv = *(const f32x4*)(RS + off);
            hv += o[ct];
            *(f32x4*)(H + off) = hv;
            if (!LAST) {
                bf16x4 p;
                p[0] = f2bf(hv.x); p[1] = f2bf(hv.y); p[2] = f2bf(hv.z); p[3] = f2bf(hv.w);
                *(bf16x4*)(HB + off) = p;
            }
        }
    }
}

extern "C" void kernel_launch(void* const* d_in, const int* in_sizes, int n_in,
                              void* d_out, int out_size, void* d_ws, size_t ws_size,
                              hipStream_t stream) {
    const float* x   = (const float*)d_in[0];
    const int*   ei  = (const int*)d_in[1];
    const float* eps = (const float*)d_in[2];
    const float* W1  = (const float*)d_in[3];
    const float* b1  = (const float*)d_in[4];
    const float* W2  = (const float*)d_in[5];
    const float* b2  = (const float*)d_in[6];
    const float* lng = (const float*)d_in[7];
    const float* lnb = (const float*)d_in[8];
    const float* skg = (const float*)d_in[9];
    const float* skb = (const float*)d_in[10];
    float* h = (float*)d_out;

    char* ws = (char*)d_ws;
    short* zbuf = (short*)ws;                         // 12,812,288 B
    short* hbb  = (short*)(ws + 12812288);            // 12,812,288 B
    short* wt   = (short*)(ws + 25624576);            //    196,608 B
    int*   rs   = (int*)  (ws + 25821184);            //    200,192 B
    int*   deg  = (int*)  (ws + 26021376);            //    200,192 B
    int*   cur  = (int*)  (ws + 26221568);            //    200,192 B
    int*   col  = (int*)  (ws + 26421760);            //  2,560,000 B
    int*   bsum = (int*)  (ws + 28981760);            //      1,024 B

    const int* srcIdx = ei;
    const int* dstIdx = ei + N_EDGES;

    init_kernel<<<(N_NODES * 32) / 256, 256, 0, stream>>>((const f32x4*)x, (bf16x4*)hbb);
    prepw_kernel<<<(6 * 16384) / 256, 256, 0, stream>>>(W1, W2, wt);

    hipMemsetAsync(deg, 0, 2 * 200192, stream);  // deg + cur contiguous
    hist_kernel<<<(N_EDGES + 255) / 256, 256, 0, stream>>>(dstIdx, deg);
    scan1_kernel<<<SCAN_NB, 256, 0, stream>>>(deg, rs, bsum);
    scan2_kernel<<<1, 256, 0, stream>>>(bsum);
    scan3_kernel<<<SCAN_NB, 256, 0, stream>>>(rs, bsum);
    fill_kernel<<<(N_EDGES + 255) / 256, 256, 0, stream>>>(srcIdx, dstIdx, rs, cur, col);

    for (int l = 0; l < LAYERS; ++l) {
        agg_kernel<<<NPAD / 16, 256, 0, stream>>>(
            (const bf16x8*)hbb, rs, deg, col, eps, l, (bf16x8*)zbuf);
        const float* rsrc = (l == 0) ? x : h;
        if (l < LAYERS - 1) {
            mlp_kernel<false><<<NPAD / 64, 256, 0, stream>>>(
                zbuf, wt + l * 16384, b1 + l * D, wt + (3 + l) * 16384, b2 + l * D,
                lng + l * D, lnb + l * D, skg + l * D, skb + l * D, rsrc, h, hbb);
        } else {
            mlp_kernel<true><<<NPAD / 64, 256, 0, stream>>>(
                zbuf, wt + l * 16384, b1 + l * D, wt + (3 + l) * 16384, b2 + l * D,
                lng + l * D, lnb + l * D, nullptr, nullptr, rsrc, h, nullptr);
        }
    }
}

// Round 5
// 223.728 us; speedup vs baseline: 15.4027x; 1.3314x over previous
//
#include <hip/hip_runtime.h>
#include <hip/hip_bf16.h>

#define N_NODES 50000
#define N_EDGES 640000
#define D 128
#define NPAD 50048   // 782 * 64
#define LAYERS 3
#define SCAN_NB 196  // ceil(50000/256)

typedef __attribute__((ext_vector_type(4))) float f32x4;
typedef __attribute__((ext_vector_type(8))) short bf16x8;
typedef __attribute__((ext_vector_type(4))) short bf16x4;

static __device__ __forceinline__ short f2bf(float f) {
    union { float f; unsigned u; } x; x.f = f;
    unsigned r = x.u + 0x7fffu + ((x.u >> 16) & 1u);  // RNE
    return (short)(r >> 16);
}
static __device__ __forceinline__ float bf2f(short s) {
    union { unsigned u; float f; } x; x.u = ((unsigned)(unsigned short)s) << 16;
    return x.f;
}

// ---------------- hb = bf16(x) ----------------
__global__ void init_kernel(const f32x4* __restrict__ in, bf16x4* __restrict__ hb) {
    int t = blockIdx.x * 256 + threadIdx.x;
    f32x4 v = in[t];
    bf16x4 p; p[0] = f2bf(v.x); p[1] = f2bf(v.y); p[2] = f2bf(v.z); p[3] = f2bf(v.w);
    hb[t] = p;
}

// ---------------- weights: wt[m][c][k] = bf16(W[m][k][c]) ----------------
__global__ void prepw_kernel(const float* __restrict__ W1, const float* __restrict__ W2,
                             short* __restrict__ wt) {
    int t = blockIdx.x * 256 + threadIdx.x;
    if (t >= 6 * 16384) return;
    int m = t >> 14, rem = t & 16383;
    int c = rem >> 7, k = rem & 127;
    const float* src = (m < 3) ? (W1 + m * 16384) : (W2 + (m - 3) * 16384);
    wt[m * 16384 + c * 128 + k] = f2bf(src[k * 128 + c]);
}

// ---------------- CSR build ----------------
__global__ void hist_kernel(const int* __restrict__ dst, int* __restrict__ deg) {
    int e = blockIdx.x * 256 + threadIdx.x;
    if (e < N_EDGES) atomicAdd(&deg[dst[e]], 1);
}

__global__ void scan1_kernel(const int* __restrict__ deg, int* __restrict__ rs,
                             int* __restrict__ bsum) {
    __shared__ int tmp[256];
    int i = blockIdx.x * 256 + threadIdx.x;
    int v = (i < N_NODES) ? deg[i] : 0;
    tmp[threadIdx.x] = v;
    __syncthreads();
    for (int off = 1; off < 256; off <<= 1) {
        int t = (threadIdx.x >= off) ? tmp[threadIdx.x - off] : 0;
        __syncthreads();
        tmp[threadIdx.x] += t;
        __syncthreads();
    }
    if (i < N_NODES) rs[i] = tmp[threadIdx.x] - v;  // exclusive
    if (threadIdx.x == 255) bsum[blockIdx.x] = tmp[255];
}

__global__ void scan2_kernel(int* __restrict__ bsum) {
    __shared__ int tmp[256];
    int v = (threadIdx.x < SCAN_NB) ? bsum[threadIdx.x] : 0;
    tmp[threadIdx.x] = v;
    __syncthreads();
    for (int off = 1; off < 256; off <<= 1) {
        int t = (threadIdx.x >= off) ? tmp[threadIdx.x - off] : 0;
        __syncthreads();
        tmp[threadIdx.x] += t;
        __syncthreads();
    }
    if (threadIdx.x < SCAN_NB) bsum[threadIdx.x] = tmp[threadIdx.x] - v;  // exclusive
}

__global__ void scan3_kernel(int* __restrict__ rs, const int* __restrict__ bsum) {
    int i = blockIdx.x * 256 + threadIdx.x;
    if (i < N_NODES) rs[i] += bsum[blockIdx.x];
}

__global__ void fill_kernel(const int* __restrict__ src, const int* __restrict__ dst,
                            const int* __restrict__ rs, int* __restrict__ cursor,
                            int* __restrict__ col) {
    int e = blockIdx.x * 256 + threadIdx.x;
    if (e >= N_EDGES) return;
    int d = dst[e];
    int p = atomicAdd(&cursor[d], 1);
    col[rs[d] + p] = src[e];
}

// ---------------- fused aggregate + GIN prep: z = bf16((1+eps)*hb + sum hb[src]) --------
__global__ __launch_bounds__(256) void agg_kernel(const bf16x8* __restrict__ hb,
                                                  const int* __restrict__ rs,
                                                  const int* __restrict__ deg,
                                                  const int* __restrict__ col,
                                                  const float* __restrict__ epsArr, int layer,
                                                  bf16x8* __restrict__ z) {
    int t = blockIdx.x * 256 + threadIdx.x;
    int node = t >> 4, lane = t & 15;
    if (node >= NPAD) return;
    bf16x8 o;
    if (node < N_NODES) {
        float acc[8] = {0.f, 0.f, 0.f, 0.f, 0.f, 0.f, 0.f, 0.f};
        int start = rs[node], dg = deg[node];
        const int* cp = col + start;
        int base = 0;
        for (; base + 4 <= dg; base += 4) {
            int c0 = cp[base], c1 = cp[base + 1], c2 = cp[base + 2], c3 = cp[base + 3];
            bf16x8 v0 = hb[(size_t)c0 * 16 + lane];
            bf16x8 v1 = hb[(size_t)c1 * 16 + lane];
            bf16x8 v2 = hb[(size_t)c2 * 16 + lane];
            bf16x8 v3 = hb[(size_t)c3 * 16 + lane];
#pragma unroll
            for (int e = 0; e < 8; ++e)
                acc[e] += (bf2f(v0[e]) + bf2f(v1[e])) + (bf2f(v2[e]) + bf2f(v3[e]));
        }
        for (; base < dg; ++base) {
            bf16x8 v = hb[(size_t)cp[base] * 16 + lane];
#pragma unroll
            for (int e = 0; e < 8; ++e) acc[e] += bf2f(v[e]);
        }
        float s = 1.0f + epsArr[layer];
        bf16x8 hv = hb[(size_t)node * 16 + lane];
#pragma unroll
        for (int e = 0; e < 8; ++e) o[e] = f2bf(fmaf(s, bf2f(hv[e]), acc[e]));
    } else {
        o = (bf16x8)(short)0;
    }
    z[(size_t)node * 16 + lane] = o;
}

// ---------------- fused MLP + LN(+skipLN+ReLU) + residual ----------------
// LDS map: [0,32K) W1 then (restaged) W2; [32K,48K) hid; [48K,48K+3K) param vectors.
// All W/param reads come from LDS -> ~3x fewer L2 requests (the R4 bottleneck).
template <bool LAST>
__global__ __launch_bounds__(256, 2) void mlp_kernel(const short* __restrict__ Z,
                                                     const short* __restrict__ Wt1,
                                                     const float* __restrict__ B1,
                                                     const short* __restrict__ Wt2,
                                                     const float* __restrict__ B2,
                                                     const float* __restrict__ G1,
                                                     const float* __restrict__ Bt1,
                                                     const float* __restrict__ G2,
                                                     const float* __restrict__ Bt2,
                                                     const float* __restrict__ RS,
                                                     float* __restrict__ H,
                                                     short* __restrict__ HB) {
    __shared__ __align__(16) char lds[49152 + 3072];
    const int t = threadIdx.x;
    const int wave = t >> 6, lane = t & 63;
    const int r = lane & 15, kq = lane >> 4;
    const int lrow = wave * 16 + r;
    const int row = blockIdx.x * 64 + lrow;
    const int swzr = (r & 7) << 4;
    const int swzl = (lrow & 7) << 4;
    const int fcol = kq * 16;   // byte offset of this lane's 4-feature group within a 512B f32 vec / *4

    // ---- prefetch Z fragments (needed first) ----
    const short* Zr = Z + (size_t)row * D + kq * 8;
    bf16x8 zb0 = *(const bf16x8*)(Zr);
    bf16x8 zb1 = *(const bf16x8*)(Zr + 32);
    bf16x8 zb2 = *(const bf16x8*)(Zr + 64);
    bf16x8 zb3 = *(const bf16x8*)(Zr + 96);
    __builtin_amdgcn_sched_barrier(0);

    // ---- stage W1 (32KB) + param vectors; issue W2 loads (held in regs) ----
    bf16x8 g2[8];
    {
        bf16x8 g1[8];
#pragma unroll
        for (int i = 0; i < 8; ++i) g1[i] = *(const bf16x8*)(Wt1 + i * 2048 + t * 8);
#pragma unroll
        for (int i = 0; i < 8; ++i) g2[i] = *(const bf16x8*)(Wt2 + i * 2048 + t * 8);
        if (t < (LAST ? 128 : 192)) {
            int which = t >> 5, chunk = t & 31;
            const float* vp = (which == 0) ? B1 : (which == 1) ? B2 : (which == 2) ? G1
                            : (which == 3) ? Bt1 : (which == 4) ? G2 : Bt2;
            *(f32x4*)(lds + 49152 + which * 512 + chunk * 16) = *(const f32x4*)(vp + chunk * 4);
        }
#pragma unroll
        for (int i = 0; i < 8; ++i) {
            int b = i * 4096 + t * 16;
            *(bf16x8*)(lds + (b ^ (((b >> 8) & 7) << 4))) = g1[i];
        }
    }
    __syncthreads();

    // ---- GEMM1 (W1 from LDS) + bias + ReLU -> p[] in regs ----
    bf16x4 p[8];
#pragma unroll
    for (int ct = 0; ct < 8; ++ct) {
        int wb = (ct * 16 + r) * 256 + kq * 16;
        f32x4 acc = {0.f, 0.f, 0.f, 0.f};
        acc = __builtin_amdgcn_mfma_f32_16x16x32_bf16(*(const bf16x8*)(lds + ((wb      ) ^ swzr)), zb0, acc, 0, 0, 0);
        acc = __builtin_amdgcn_mfma_f32_16x16x32_bf16(*(const bf16x8*)(lds + ((wb +  64) ^ swzr)), zb1, acc, 0, 0, 0);
        acc = __builtin_amdgcn_mfma_f32_16x16x32_bf16(*(const bf16x8*)(lds + ((wb + 128) ^ swzr)), zb2, acc, 0, 0, 0);
        acc = __builtin_amdgcn_mfma_f32_16x16x32_bf16(*(const bf16x8*)(lds + ((wb + 192) ^ swzr)), zb3, acc, 0, 0, 0);
        f32x4 bias = *(const f32x4*)(lds + 49152 + 0 + ct * 64 + fcol);
        p[ct][0] = f2bf(fmaxf(acc[0] + bias.x, 0.0f));
        p[ct][1] = f2bf(fmaxf(acc[1] + bias.y, 0.0f));
        p[ct][2] = f2bf(fmaxf(acc[2] + bias.z, 0.0f));
        p[ct][3] = f2bf(fmaxf(acc[3] + bias.w, 0.0f));
    }
    __syncthreads();   // all W1 LDS reads complete

    // ---- issue residual loads (latency hides under GEMM2) ----
    f32x4 rsv[8] = {};
    if (row < N_NODES) {
#pragma unroll
        for (int ct = 0; ct < 8; ++ct)
            rsv[ct] = *(const f32x4*)(RS + (size_t)row * D + ct * 16 + kq * 4);
    }
    __builtin_amdgcn_sched_barrier(0);

    // ---- restage W2 into [0,32K) (regs -> LDS), write hid into [32K,48K) ----
#pragma unroll
    for (int i = 0; i < 8; ++i) {
        int b = i * 4096 + t * 16;
        *(bf16x8*)(lds + (b ^ (((b >> 8) & 7) << 4))) = g2[i];
    }
#pragma unroll
    for (int ct = 0; ct < 8; ++ct)
        *(bf16x4*)(lds + 32768 + ((lrow * 256 + ct * 32 + kq * 8) ^ swzl)) = p[ct];
    __syncthreads();

    // ---- hid B-fragments from LDS ----
    bf16x8 hb0 = *(const bf16x8*)(lds + 32768 + ((lrow * 256 +   0 + kq * 16) ^ swzl));
    bf16x8 hb1 = *(const bf16x8*)(lds + 32768 + ((lrow * 256 +  64 + kq * 16) ^ swzl));
    bf16x8 hb2 = *(const bf16x8*)(lds + 32768 + ((lrow * 256 + 128 + kq * 16) ^ swzl));
    bf16x8 hb3 = *(const bf16x8*)(lds + 32768 + ((lrow * 256 + 192 + kq * 16) ^ swzl));

    // ---- GEMM2 (W2 from LDS) + bias ----
    f32x4 o[8];
#pragma unroll
    for (int ct = 0; ct < 8; ++ct) {
        int wb = (ct * 16 + r) * 256 + kq * 16;
        f32x4 acc = {0.f, 0.f, 0.f, 0.f};
        acc = __builtin_amdgcn_mfma_f32_16x16x32_bf16(*(const bf16x8*)(lds + ((wb      ) ^ swzr)), hb0, acc, 0, 0, 0);
        acc = __builtin_amdgcn_mfma_f32_16x16x32_bf16(*(const bf16x8*)(lds + ((wb +  64) ^ swzr)), hb1, acc, 0, 0, 0);
        acc = __builtin_amdgcn_mfma_f32_16x16x32_bf16(*(const bf16x8*)(lds + ((wb + 128) ^ swzr)), hb2, acc, 0, 0, 0);
        acc = __builtin_amdgcn_mfma_f32_16x16x32_bf16(*(const bf16x8*)(lds + ((wb + 192) ^ swzr)), hb3, acc, 0, 0, 0);
        f32x4 bias = *(const f32x4*)(lds + 49152 + 512 + ct * 64 + fcol);
        o[ct] = acc + bias;
    }

    // ---- LayerNorm over the row ----
    float s = 0.f, q = 0.f;
#pragma unroll
    for (int ct = 0; ct < 8; ++ct) {
        s += o[ct].x + o[ct].y + o[ct].z + o[ct].w;
        q += o[ct].x * o[ct].x + o[ct].y * o[ct].y + o[ct].z * o[ct].z + o[ct].w * o[ct].w;
    }
    s += __shfl_xor(s, 16, 64); q += __shfl_xor(q, 16, 64);
    s += __shfl_xor(s, 32, 64); q += __shfl_xor(q, 32, 64);
    float mu = s * (1.0f / D);
    float rstd = rsqrtf(q * (1.0f / D) - mu * mu + 1e-5f);
#pragma unroll
    for (int ct = 0; ct < 8; ++ct) {
        f32x4 g = *(const f32x4*)(lds + 49152 + 1024 + ct * 64 + fcol);
        f32x4 b = *(const f32x4*)(lds + 49152 + 1536 + ct * 64 + fcol);
        o[ct] = (o[ct] - mu) * rstd * g + b;
    }

    if (!LAST) {
        float s2 = 0.f, q2 = 0.f;
#pragma unroll
        for (int ct = 0; ct < 8; ++ct) {
            s2 += o[ct].x + o[ct].y + o[ct].z + o[ct].w;
            q2 += o[ct].x * o[ct].x + o[ct].y * o[ct].y + o[ct].z * o[ct].z + o[ct].w * o[ct].w;
        }
        s2 += __shfl_xor(s2, 16, 64); q2 += __shfl_xor(q2, 16, 64);
        s2 += __shfl_xor(s2, 32, 64); q2 += __shfl_xor(q2, 32, 64);
        float mu2 = s2 * (1.0f / D);
        float rstd2 = rsqrtf(q2 * (1.0f / D) - mu2 * mu2 + 1e-5f);
#pragma unroll
        for (int ct = 0; ct < 8; ++ct) {
            f32x4 g = *(const f32x4*)(lds + 49152 + 2048 + ct * 64 + fcol);
            f32x4 b = *(const f32x4*)(lds + 49152 + 2560 + ct * 64 + fcol);
            f32x4 y = (o[ct] - mu2) * rstd2 * g + b;
            y.x = fmaxf(y.x, 0.f); y.y = fmaxf(y.y, 0.f);
            y.z = fmaxf(y.z, 0.f); y.w = fmaxf(y.w, 0.f);
            o[ct] = y;
        }
    }

    // ---- residual + store ----
    if (row < N_NODES) {
#pragma unroll
        for (int ct = 0; ct < 8; ++ct) {
            size_t off = (size_t)row * D + ct * 16 + kq * 4;
            f32x4 hv = rsv[ct] + o[ct];
            *(f32x4*)(H + off) = hv;
            if (!LAST) {
                bf16x4 pb;
                pb[0] = f2bf(hv.x); pb[1] = f2bf(hv.y); pb[2] = f2bf(hv.z); pb[3] = f2bf(hv.w);
                *(bf16x4*)(HB + off) = pb;
            }
        }
    }
}

extern "C" void kernel_launch(void* const* d_in, const int* in_sizes, int n_in,
                              void* d_out, int out_size, void* d_ws, size_t ws_size,
                              hipStream_t stream) {
    const float* x   = (const float*)d_in[0];
    const int*   ei  = (const int*)d_in[1];
    const float* eps = (const float*)d_in[2];
    const float* W1  = (const float*)d_in[3];
    const float* b1  = (const float*)d_in[4];
    const float* W2  = (const float*)d_in[5];
    const float* b2  = (const float*)d_in[6];
    const float* lng = (const float*)d_in[7];
    const float* lnb = (const float*)d_in[8];
    const float* skg = (const float*)d_in[9];
    const float* skb = (const float*)d_in[10];
    float* h = (float*)d_out;

    char* ws = (char*)d_ws;
    short* zbuf = (short*)ws;                         // 12,812,288 B
    short* hbb  = (short*)(ws + 12812288);            // 12,812,288 B
    short* wt   = (short*)(ws + 25624576);            //    196,608 B
    int*   rs   = (int*)  (ws + 25821184);            //    200,192 B
    int*   deg  = (int*)  (ws + 26021376);            //    200,192 B
    int*   cur  = (int*)  (ws + 26221568);            //    200,192 B
    int*   col  = (int*)  (ws + 26421760);            //  2,560,000 B
    int*   bsum = (int*)  (ws + 28981760);            //      1,024 B

    const int* srcIdx = ei;
    const int* dstIdx = ei + N_EDGES;

    init_kernel<<<(N_NODES * 32) / 256, 256, 0, stream>>>((const f32x4*)x, (bf16x4*)hbb);
    prepw_kernel<<<(6 * 16384) / 256, 256, 0, stream>>>(W1, W2, wt);

    hipMemsetAsync(deg, 0, 2 * 200192, stream);  // deg + cur contiguous
    hist_kernel<<<(N_EDGES + 255) / 256, 256, 0, stream>>>(dstIdx, deg);
    scan1_kernel<<<SCAN_NB, 256, 0, stream>>>(deg, rs, bsum);
    scan2_kernel<<<1, 256, 0, stream>>>(bsum);
    scan3_kernel<<<SCAN_NB, 256, 0, stream>>>(rs, bsum);
    fill_kernel<<<(N_EDGES + 255) / 256, 256, 0, stream>>>(srcIdx, dstIdx, rs, cur, col);

    for (int l = 0; l < LAYERS; ++l) {
        agg_kernel<<<NPAD / 16, 256, 0, stream>>>(
            (const bf16x8*)hbb, rs, deg, col, eps, l, (bf16x8*)zbuf);
        const float* rsrc = (l == 0) ? x : h;
        if (l < LAYERS - 1) {
            mlp_kernel<false><<<NPAD / 64, 256, 0, stream>>>(
                zbuf, wt + l * 16384, b1 + l * D, wt + (3 + l) * 16384, b2 + l * D,
                lng + l * D, lnb + l * D, skg + l * D, skb + l * D, rsrc, h, hbb);
        } else {
            mlp_kernel<true><<<NPAD / 64, 256, 0, stream>>>(
                zbuf, wt + l * 16384, b1 + l * D, wt + (3 + l) * 16384, b2 + l * D,
                lng + l * D, lnb + l * D, nullptr, nullptr, rsrc, h, nullptr);
        }
    }
}